// Round 5
// baseline (166.144 us; speedup 1.0000x reference)
//
#include <hip/hip_runtime.h>
#include <stdint.h>

#define N_ROWS 4096
#define D_DIM  1024
#define KBYTES 2048   // bytes per row in bf16
#define T_TEMP 0.15f

#define AS1 __attribute__((address_space(1)))
#define AS3 __attribute__((address_space(3)))

typedef float  f32x16 __attribute__((ext_vector_type(16)));
typedef __bf16 bf16x8 __attribute__((ext_vector_type(8)));

__device__ __forceinline__ unsigned int f2bf(float f) {
  unsigned u = __float_as_uint(f);
  u += 0x7FFF + ((u >> 16) & 1);   // RNE
  return u >> 16;
}

__device__ __forceinline__ float wsum(float v) {
#pragma unroll
  for (int m = 32; m >= 1; m >>= 1) v += __shfl_xor(v, m, 64);
  return v;
}
__device__ __forceinline__ float wmax(float v) {
#pragma unroll
  for (int m = 32; m >= 1; m >>= 1) v = fmaxf(v, __shfl_xor(v, m, 64));
  return v;
}

// One WAVE per row (no barriers): norms, x.y dot (-> log pos), softmax-JS
// per-row term -> js[row], bf16 casts into Bb = [x;y]. Zeroes rowsum.
__global__ __launch_bounds__(256) void prep_kernel(
    const float* __restrict__ x, const float* __restrict__ y,
    unsigned short* __restrict__ Bb, float* __restrict__ inv_n,
    float* __restrict__ logpos, float* __restrict__ js,
    float* __restrict__ rowsum) {
  if (threadIdx.x < 4) rowsum[blockIdx.x * 4 + threadIdx.x] = 0.0f;

  const int wid = threadIdx.x >> 6, lane = threadIdx.x & 63;
  const int row = blockIdx.x * 4 + wid;
  const float4* xp = (const float4*)(x + (size_t)row * D_DIM) + lane * 4;
  const float4* yp = (const float4*)(y + (size_t)row * D_DIM) + lane * 4;

  float xv[16], yv[16];
#pragma unroll
  for (int i = 0; i < 4; ++i) {
    float4 a = xp[i], b = yp[i];
    xv[i*4+0]=a.x; xv[i*4+1]=a.y; xv[i*4+2]=a.z; xv[i*4+3]=a.w;
    yv[i*4+0]=b.x; yv[i*4+1]=b.y; yv[i*4+2]=b.z; yv[i*4+3]=b.w;
  }

  float sx2=0.f, sy2=0.f, sxy=0.f, mx=-1e30f, my=-1e30f;
#pragma unroll
  for (int k = 0; k < 16; ++k) {
    sx2 = fmaf(xv[k], xv[k], sx2);
    sy2 = fmaf(yv[k], yv[k], sy2);
    sxy = fmaf(xv[k], yv[k], sxy);
    mx = fmaxf(mx, xv[k]); my = fmaxf(my, yv[k]);
  }
  sx2 = wsum(sx2); sy2 = wsum(sy2); sxy = wsum(sxy);
  mx = wmax(mx);  my = wmax(my);

  float ex[16], ey[16], sex=0.f, sey=0.f;
#pragma unroll
  for (int k = 0; k < 16; ++k) {
    ex[k] = __expf(xv[k] - mx); ey[k] = __expf(yv[k] - my);
    sex += ex[k]; sey += ey[k];
  }
  sex = wsum(sex); sey = wsum(sey);
  const float lsex = __logf(sex), lsey = __logf(sey);
  const float rsex = 1.f / sex,  rsey = 1.f / sey;

  float term = 0.f;
#pragma unroll
  for (int k = 0; k < 16; ++k) {
    float a = ex[k] * rsex, b = ey[k] * rsey;
    float lm = __logf(0.5f * (a + b));
    term += a * ((xv[k] - mx - lsex) - lm) + b * ((yv[k] - my - lsey) - lm);
  }
  term = wsum(term);

  if (lane == 0) {
    const float nx = sqrtf(sx2), ny = sqrtf(sy2);
    inv_n[row] = 1.f / nx;
    inv_n[N_ROWS + row] = 1.f / ny;
    logpos[row] = sxy / fmaxf(nx * ny, 1e-8f) / T_TEMP;  // ln(pos)
    js[row] = term;
  }

  int p[8], q[8];
#pragma unroll
  for (int w = 0; w < 8; ++w) {
    p[w] = f2bf(xv[2*w]) | (f2bf(xv[2*w+1]) << 16);
    q[w] = f2bf(yv[2*w]) | (f2bf(yv[2*w+1]) << 16);
  }
  int4* ox = (int4*)(Bb + (size_t)row * D_DIM + lane * 16);
  int4* oy = (int4*)(Bb + (size_t)(N_ROWS + row) * D_DIM + lane * 16);
  ox[0] = make_int4(p[0], p[1], p[2], p[3]);
  ox[1] = make_int4(p[4], p[5], p[6], p[7]);
  oy[0] = make_int4(q[0], q[1], q[2], q[3]);
  oy[1] = make_int4(q[4], q[5], q[6], q[7]);
}

// ===== 8-phase 256x256 GEMM, 32x32x16 MFMA, fused exp-cosine epilogue =====
// LDS k-major [buf][kk][256 rows][32 bf16] (64B rows, chunk ^= (row>>1)&3,
// measured 0 conflicts). 8 waves (2M x 4N), per-wave C = 128x64 = 4x2 tiles
// of 32x32. Per K-tile(64): 4 phases, one k-step(16) each: 6 ds_read_b128 +
// 8 MFMA (balanced). Counted vmcnt(4) twice per K-tile; never 0 in main loop.
#define GLL(src, dst) __builtin_amdgcn_global_load_lds((const AS1 void*)(src), (AS3 void*)(dst), 16, 0, 0)
#define ST_A(kt1, h, bufv) do { \
  GLL(gA + (size_t)(kt1)*128 + (h)*64,                        dA + (bufv)*32768 + (h)*16384); \
  GLL(gA + 128*(size_t)KBYTES + (size_t)(kt1)*128 + (h)*64,   dA + (bufv)*32768 + (h)*16384 + 8192); } while(0)
#define ST_B(kt1, h, bufv) do { \
  GLL(gB + (size_t)(kt1)*128 + (h)*64,                        dB + (bufv)*32768 + (h)*16384); \
  GLL(gB + 128*(size_t)KBYTES + (size_t)(kt1)*128 + (h)*64,   dB + (bufv)*32768 + (h)*16384 + 8192); } while(0)
// phase read: k-step s (0..3) of buffer bufv; all offsets compile-time.
#define RDP(s, bufv) do { \
  const char* _pa = ((s) & 1) ? lAo : lAe; \
  const char* _pb = ((s) & 1) ? lBo : lBe; \
  _Pragma("unroll") \
  for (int mt_ = 0; mt_ < 4; ++mt_) \
    a[mt_] = *(const bf16x8*)(_pa + (bufv)*32768 + ((s)>>1)*16384 + mt_*2048); \
  b[0] = *(const bf16x8*)(_pb + (bufv)*32768 + ((s)>>1)*16384); \
  b[1] = *(const bf16x8*)(_pb + (bufv)*32768 + ((s)>>1)*16384 + 2048); } while(0)
#define MM8 do { _Pragma("unroll") \
  for (int mt_ = 0; mt_ < 4; ++mt_) { \
    acc[mt_][0] = __builtin_amdgcn_mfma_f32_32x32x16_bf16(a[mt_], b[0], acc[mt_][0], 0, 0, 0); \
    acc[mt_][1] = __builtin_amdgcn_mfma_f32_32x32x16_bf16(a[mt_], b[1], acc[mt_][1], 0, 0, 0); } } while(0)
#define BARR  __builtin_amdgcn_s_barrier()
#define LGKM0 asm volatile("s_waitcnt lgkmcnt(0)")
#define VM4   asm volatile("s_waitcnt vmcnt(4)" ::: "memory")
#define VM0   asm volatile("s_waitcnt vmcnt(0)" ::: "memory")
#define PR1   __builtin_amdgcn_s_setprio(1)
#define PR0   __builtin_amdgcn_s_setprio(0)

#define K_TILE(bufc, kn) do { \
  RDP(0, bufc); ST_A(kn, 0, (bufc)^1); BARR; LGKM0; PR1; MM8; PR0; BARR; \
  RDP(1, bufc); ST_B(kn, 0, (bufc)^1); BARR; LGKM0; PR1; MM8; PR0; VM4; BARR; \
  RDP(2, bufc); ST_A(kn, 1, (bufc)^1); BARR; LGKM0; PR1; MM8; PR0; BARR; \
  RDP(3, bufc); ST_B(kn, 1, (bufc)^1); BARR; LGKM0; PR1; MM8; PR0; VM4; BARR; \
} while(0)
#define K_TAIL(bufc) do { \
  RDP(0, bufc); BARR; LGKM0; PR1; MM8; PR0; BARR; \
  RDP(1, bufc); BARR; LGKM0; PR1; MM8; PR0; VM0; BARR; \
  RDP(2, bufc); BARR; LGKM0; PR1; MM8; PR0; BARR; \
  RDP(3, bufc); BARR; LGKM0; PR1; MM8; PR0; BARR; \
} while(0)

__global__ __launch_bounds__(512, 2) void gemm_fused(
    const unsigned short* __restrict__ Bb, const float* __restrict__ inv_n,
    float* __restrict__ rowsum) {
  __shared__ __align__(16) unsigned short As[2][2][256][32];
  __shared__ __align__(16) unsigned short Bs[2][2][256][32];
  const int tid = threadIdx.x;
  const int wid = tid >> 6, lane = tid & 63;
  const int l31 = lane & 31, l5 = lane >> 5;
  const int wm = wid >> 2, wn = wid & 3;

  // chunked XCD swizzle: 512 blocks -> 8 XCD chunks of 8x8 tile blocks
  const int id = blockIdx.x;
  const int u = (id & 7) * 64 + (id >> 3);
  const int ch = u >> 6, lcl = u & 63;
  const int bx = ((ch & 1) << 3) + (lcl >> 3);
  const int by = ((ch >> 1) << 3) + (lcl & 7);
  const int grow0 = bx * 256, gcol0 = by * 256;

  f32x16 acc[4][2] = {};
  bf16x8 a[4], b[2];

  // staging: per-lane global source, chunk pre-swizzled by (row>>1)&3
  const int srow = wid * 16 + (lane >> 2);
  const int gch = (lane & 3) ^ ((lane >> 3) & 3);
  const char* gA = (const char*)Bb + (size_t)(grow0 + srow) * KBYTES + gch * 16;
  const char* gB = (const char*)Bb + (size_t)(gcol0 + srow) * KBYTES + gch * 16;
  char* dA = (char*)As + wid * 1024;
  char* dB = (char*)Bs + wid * 1024;

  // fragment-read bases: row = panel + l31; chunk = (2*(s&1) + l5) ^ xr
  const int xr = (l31 >> 1) & 3;
  const char* lAe = (const char*)As + (wm * 128 + l31) * 64 + ((l5 ^ xr) << 4);
  const char* lAo = (const char*)As + (wm * 128 + l31) * 64 + (((2 + l5) ^ xr) << 4);
  const char* lBe = (const char*)Bs + (wn * 64 + l31) * 64 + ((l5 ^ xr) << 4);
  const char* lBo = (const char*)Bs + (wn * 64 + l31) * 64 + (((2 + l5) ^ xr) << 4);

  // prologue: stage tile 0 into buf 0
  ST_A(0, 0, 0); ST_B(0, 0, 0); ST_A(0, 1, 0); ST_B(0, 1, 0);
  VM4;   // A-kh0,B-kh0 of tile 0 complete
  BARR;

  for (int kt = 0; kt < 14; kt += 2) { K_TILE(0, kt + 1); K_TILE(1, kt + 2); }
  K_TILE(0, 15);
  K_TAIL(1);

  // ===== epilogue (32x32 C/D layout: col=l31, row=(r&3)+8*(r>>2)+4*l5) =====
  const float C = 1.4426950408889634f / T_TEMP;   // log2(e)/T
  const float invc0 = inv_n[gcol0 + wn * 64 + l31] * C;
  const float invc1 = inv_n[gcol0 + wn * 64 + 32 + l31] * C;
  const int j0 = gcol0 + wn * 64 + l31;
  const int j1 = j0 + 32;

#pragma unroll
  for (int mt = 0; mt < 4; ++mt) {
    const int ibase = grow0 + wm * 128 + mt * 32;
    float4 ir[4];
#pragma unroll
    for (int g = 0; g < 4; ++g)
      ir[g] = *(const float4*)&inv_n[ibase + g * 8 + 4 * l5];

    float rp[16];
#pragma unroll
    for (int r = 0; r < 16; ++r) {
      const int row = (r & 3) + 8 * (r >> 2) + 4 * l5;
      const int i = ibase + row;
      const float sc = ((const float*)&ir[r >> 2])[r & 3];
      float e0 = exp2f(acc[mt][0][r] * sc * invc0);
      float e1 = exp2f(acc[mt][1][r] * sc * invc1);
      if (j0 == i || j0 == i + N_ROWS) e0 = 0.0f;
      if (j1 == i || j1 == i + N_ROWS) e1 = 0.0f;
      rp[r] = e0 + e1;
    }
#pragma unroll
    for (int mk = 1; mk <= 16; mk <<= 1)
#pragma unroll
      for (int r = 0; r < 16; ++r)
        rp[r] += __shfl_xor(rp[r], mk, 32);
    if (l31 == 0) {
#pragma unroll
      for (int r = 0; r < 16; ++r)
        atomicAdd(&rowsum[ibase + (r & 3) + 8 * (r >> 2) + 4 * l5], rp[r]);
    }
  }
}

// Single block: cumsum(rowsum) -> sum(log(neg) - logpos) + sum(js) -> out[0]
__global__ __launch_bounds__(256) void final_kernel(
    const float* __restrict__ rowsum, const float* __restrict__ logpos,
    const float* __restrict__ js, float* __restrict__ out) {
  __shared__ float scan[256];
  __shared__ double ds[4];
  __shared__ float fs[4];
  const int tid = threadIdx.x;
  float loc[16];
  float run = 0.f, jl = 0.f;
#pragma unroll
  for (int k = 0; k < 16; ++k) {
    loc[k] = rowsum[tid * 16 + k];
    run += loc[k];
    jl += js[tid * 16 + k];
  }
  scan[tid] = run;
  __syncthreads();
  for (int d = 1; d < 256; d <<= 1) {
    float add = (tid >= d) ? scan[tid - d] : 0.0f;
    __syncthreads();
    scan[tid] += add;
    __syncthreads();
  }
  float c = scan[tid] - run;  // exclusive prefix
  double acc = 0.0;
#pragma unroll
  for (int k = 0; k < 16; ++k) {
    c += loc[k];
    acc += (double)(logf(c) - logpos[tid * 16 + k]);
  }
#pragma unroll
  for (int m = 32; m >= 1; m >>= 1) {
    acc += __shfl_xor(acc, m, 64);
    jl  += __shfl_xor(jl, m, 64);
  }
  if ((tid & 63) == 0) { ds[tid >> 6] = acc; fs[tid >> 6] = jl; }
  __syncthreads();
  if (tid == 0) {
    const double nce = ds[0] + ds[1] + ds[2] + ds[3];
    const double jst = (double)(fs[0] + fs[1] + fs[2] + fs[3]);
    out[0] = (float)(nce + jst / (2.0 * N_ROWS));
  }
}

extern "C" void kernel_launch(void* const* d_in, const int* in_sizes, int n_in,
                              void* d_out, int out_size, void* d_ws, size_t ws_size,
                              hipStream_t stream) {
  const float* x = (const float*)d_in[0];
  const float* y = (const float*)d_in[1];
  float* out = (float*)d_out;

  char* ws = (char*)d_ws;
  unsigned short* Bb = (unsigned short*)ws;                 // [8192][1024] bf16, 16 MB
  float* inv_n  = (float*)(ws + (size_t)16 * 1024 * 1024);  // 8192
  float* logpos = inv_n + 8192;                             // 4096
  float* rowsum = logpos + 4096;                            // 4096
  float* js     = rowsum + 4096;                            // 4096

  prep_kernel<<<N_ROWS / 4, 256, 0, stream>>>(x, y, Bb, inv_n, logpos, js, rowsum);
  gemm_fused<<<512, 512, 0, stream>>>(Bb, inv_n, rowsum);
  final_kernel<<<1, 256, 0, stream>>>(rowsum, logpos, js, out);
}